// Round 5
// baseline (1509.011 us; speedup 1.0000x reference)
//
#include <hip/hip_runtime.h>
#include <math.h>

#define BN_ 2
#define CIN 256
#define HH_ 64
#define W2_ 128
#define PP 8192
#define EPS_ 1e-5f
#define QSCL 0.17677669529663687f

typedef __attribute__((ext_vector_type(4)))  float  f32x4;
typedef __attribute__((ext_vector_type(16))) float  f32x16;
typedef __attribute__((ext_vector_type(8)))  short  short8;
typedef __attribute__((ext_vector_type(8)))  __bf16 bf16x8;

static __device__ __forceinline__ short f2bf(float x) {
    unsigned u = __builtin_bit_cast(unsigned, x);
    u = u + 0x7FFFu + ((u >> 16) & 1u);
    return (short)(u >> 16);
}
static __device__ __forceinline__ float bf2f(short s) {
    unsigned u = ((unsigned)(unsigned short)s) << 16;
    return __builtin_bit_cast(float, u);
}
static __device__ __forceinline__ f32x4 mfma16(short8 a, short8 b, f32x4 c) {
    return __builtin_amdgcn_mfma_f32_16x16x32_bf16(
        __builtin_bit_cast(bf16x8, a), __builtin_bit_cast(bf16x8, b), c, 0, 0, 0);
}
static __device__ __forceinline__ f32x16 mfma32(short8 a, short8 b, f32x16 c) {
    return __builtin_amdgcn_mfma_f32_32x32x16_bf16(
        __builtin_bit_cast(bf16x8, a), __builtin_bit_cast(bf16x8, b), c, 0, 0, 0);
}
// swizzled byte offset for [row][RB bytes] LDS tiles (T2/G4 XOR form).
// NOTE: must be applied to the FULL address on BOTH writer and reader sides —
// for RB=64 the XOR's bit 6 crosses rows (bijective row pair-swap), so
// "row*RB + (chunk^xor)" on one side and "(row*RB+chunk)^xor" on the other
// DESYNCHRONIZE (round-4 failure: sK2 rows 5,7 mod 8 read stale LDS).
static __device__ __forceinline__ int swz(int row, int chunk, int RB) {
    return (row * RB + chunk) ^ ((row & 7) << 4);
}

// ---------------- Kernel A: feats fp32 -> bf16-hi ----------------
__global__ __launch_bounds__(256) void fsplit_kernel(const float* __restrict__ f,
                                                     short* __restrict__ fh) {
    int i = (blockIdx.x * 256 + threadIdx.x) * 8;   // 4,194,304 elems total
    float4 a = *(const float4*)&f[i];
    float4 c = *(const float4*)&f[i + 4];
    short8 o;
    o[0] = f2bf(a.x); o[1] = f2bf(a.y); o[2] = f2bf(a.z); o[3] = f2bf(a.w);
    o[4] = f2bf(c.x); o[5] = f2bf(c.y); o[6] = f2bf(c.z); o[7] = f2bf(c.w);
    *(short8*)&fh[i] = o;
}

// ---------------- Kernel 0: conv_w (256,1024,3,3) -> wt_hi/lo[d][o][c] ----------------
__global__ __launch_bounds__(256) void wsplit_kernel(const float* __restrict__ cw,
                                                     short* __restrict__ wt_hi,
                                                     short* __restrict__ wt_lo) {
    __shared__ float tile[2304];
    const int o = blockIdx.x, c0 = blockIdx.y * 256, t = threadIdx.x;
    for (int i = t; i < 2304; i += 256) tile[i] = cw[(size_t)o * 9216 + (size_t)c0 * 9 + i];
    __syncthreads();
    #pragma unroll
    for (int d = 0; d < 9; ++d) {
        float v = tile[t * 9 + d];
        short h = f2bf(v);
        size_t off = ((size_t)(d * 256 + o)) * 1024 + c0 + t;
        wt_hi[off] = h;
        wt_lo[off] = f2bf(v - bf2f(h));
    }
}

// ---------------- Kernel 1: QKV GEMM via MFMA, BN folded, hi/lo bf16 outputs ----------------
// C[320 r][16384 n] per scale; q/k tiles computed operand-swapped for coalesced [n][32] store.
__global__ __launch_bounds__(512, 4) void qkv_kernel(
    const short* __restrict__ featsH,
    const float* __restrict__ qw, const float* __restrict__ qb,
    const float* __restrict__ qg, const float* __restrict__ qbe,
    const float* __restrict__ qm, const float* __restrict__ qv,
    const float* __restrict__ kw, const float* __restrict__ kb,
    const float* __restrict__ kg, const float* __restrict__ kbe,
    const float* __restrict__ km, const float* __restrict__ kvv,
    const float* __restrict__ vw, const float* __restrict__ vb,
    short* __restrict__ qT_hi, short* __restrict__ qT_lo,
    short* __restrict__ kT_hi, short* __restrict__ kT_lo,
    short* __restrict__ v_hi,  short* __restrict__ v_lo,
    int s, int lg2L)
{
    const int L = 1 << lg2L;
    const int NT = (L < 256) ? L : 256;
    const int lgNT = (lg2L < 8) ? lg2L : 8;
    const int t = threadIdx.x, w = t >> 6, l = t & 63;
    const int n0 = blockIdx.x * NT;
    const int y = blockIdx.y;                 // r-tile: rows y*64 .. y*64+63
    const int wi = n0 >> lg2L;
    const int b = wi & 1;
    const int l0 = n0 & (L - 1);

    __shared__ short sA[2][4096];             // [pl][swz(rr, c*2, 128)/2]  64r x 64c
    __shared__ short sB[16384];               // [swz(nn, c*2, 128)/2]     256n x 64c (hi)
    __shared__ int   pmap[256];
    __shared__ float sAl[64], sBt[64];

    if (t < NT) {
        int n = n0 + t;
        int wi_ = n >> lg2L, lq = n & (L - 1);
        int hs = 64 / s, wsz = 64 / s;
        int i_blk = wi_ / (s * 2), j_blk = (wi_ / 2) % s;
        int hh = lq / (wsz * 2), rem = lq % (wsz * 2);
        pmap[t] = (i_blk * hs + hh) * W2_ + (rem & 1) * 64 + j_blk * wsz + (rem >> 1);
    }
    if (t < 64) {
        int r = y * 64 + t;
        float alpha, beta;
        if (r < 32) {
            float sc = qg[r] / sqrtf(qv[r] + EPS_);
            alpha = sc * QSCL; beta = (qb[r] * sc + qbe[r] - qm[r] * sc) * QSCL;
        } else if (r < 64) {
            int u = r - 32;
            float sc = kg[u] / sqrtf(kvv[u] + EPS_);
            alpha = sc; beta = kb[u] * sc + kbe[u] - km[u] * sc;
        } else {
            alpha = 1.f; beta = vb[r - 64];
        }
        sAl[t] = alpha; sBt[t] = beta;
    }
    __syncthreads();

    const int rt = w & 1, nc = w >> 1;
    const int NF = NT >> 7;                   // 2 (NT=256) or 1 (NT=128)
    f32x16 accA = {}, accB = {};

    #pragma unroll 1
    for (int c0 = 0; c0 < 256; c0 += 64) {
        // stage A: weights fp32 -> hi/lo
        #pragma unroll
        for (int i = 0; i < 8; ++i) {
            int rr = i * 8 + w;
            int r = y * 64 + rr;
            const float* wp = (r < 32) ? (qw + r * 256)
                             : (r < 64) ? (kw + (r - 32) * 256)
                                        : (vw + (size_t)(r - 64) * 256);
            float v = wp[c0 + l];
            short h = f2bf(v);
            int so = swz(rr, l * 2, 128) >> 1;
            sA[0][so] = h;
            sA[1][so] = f2bf(v - bf2f(h));
        }
        // stage B: gathered bf16-hi feats
        {
            int cnt = NT >> 3;
            for (int i = 0; i < cnt; ++i) {
                int idx = i * 512 + t;
                int nn = idx & (NT - 1);
                int cc = idx >> lgNT;
                short hv = featsH[(size_t)(b * 256 + c0 + cc) * PP + pmap[nn]];
                sB[swz(nn, cc * 2, 128) >> 1] = hv;
            }
        }
        __syncthreads();
        #pragma unroll
        for (int kc = 0; kc < 4; ++kc) {
            const int ch = kc * 32 + (l >> 5) * 16;
            int ra = rt * 32 + (l & 31);
            int so = swz(ra, ch, 128) >> 1;
            short8 ah = *(const short8*)&sA[0][so];
            short8 al = *(const short8*)&sA[1][so];
            int nnb = nc * (NT >> 2) + (l & 31);
            int sb0 = swz(nnb, ch, 128) >> 1;
            short8 b0 = *(const short8*)&sB[sb0];
            if (y == 0) { accA = mfma32(b0, ah, accA); accA = mfma32(b0, al, accA); }
            else        { accA = mfma32(ah, b0, accA); accA = mfma32(al, b0, accA); }
            if (NF == 2) {
                int nnb1 = nnb + 32;
                int sb1 = swz(nnb1, ch, 128) >> 1;
                short8 b1 = *(const short8*)&sB[sb1];
                if (y == 0) { accB = mfma32(b1, ah, accB); accB = mfma32(b1, al, accB); }
                else        { accB = mfma32(ah, b1, accB); accB = mfma32(al, b1, accB); }
            }
        }
        __syncthreads();
    }

    if (y == 0) {
        // swapped: D[n][r]; col = r = rt*32+(l&31) -> coalesced u16 stores
        int r = rt * 32 + (l & 31);
        float alpha = sAl[r], beta = sBt[r];
        short* oh = (r < 32) ? qT_hi : kT_hi;
        short* ol = (r < 32) ? qT_lo : kT_lo;
        int rr = r & 31;
        #pragma unroll
        for (int reg = 0; reg < 16; ++reg) {
            int nl = nc * (NT >> 2) + (reg & 3) + 8 * (reg >> 2) + 4 * (l >> 5);
            float v = accA[reg] * alpha + beta;
            short h = f2bf(v);
            size_t off = (size_t)(n0 + nl) * 32 + rr;
            oh[off] = h;
            ol[off] = f2bf(v - bf2f(h));
        }
        if (NF == 2) {
            #pragma unroll
            for (int reg = 0; reg < 16; ++reg) {
                int nl = nc * (NT >> 2) + 32 + (reg & 3) + 8 * (reg >> 2) + 4 * (l >> 5);
                float v = accB[reg] * alpha + beta;
                short h = f2bf(v);
                size_t off = (size_t)(n0 + nl) * 32 + rr;
                oh[off] = h;
                ol[off] = f2bf(v - bf2f(h));
            }
        }
    } else {
        #pragma unroll
        for (int reg = 0; reg < 16; ++reg) {
            int rr = rt * 32 + (reg & 3) + 8 * (reg >> 2) + 4 * (l >> 5);
            int vr = y * 64 - 64 + rr;
            int nl = nc * (NT >> 2) + (l & 31);
            float v = accA[reg] * sAl[rr] + sBt[rr];
            short h = f2bf(v);
            size_t off = ((size_t)wi * 256 + vr) * L + (l0 + nl);
            v_hi[off] = h;
            v_lo[off] = f2bf(v - bf2f(h));
        }
        if (NF == 2) {
            #pragma unroll
            for (int reg = 0; reg < 16; ++reg) {
                int rr = rt * 32 + (reg & 3) + 8 * (reg >> 2) + 4 * (l >> 5);
                int vr = y * 64 - 64 + rr;
                int nl = nc * (NT >> 2) + 32 + (l & 31);
                float v = accB[reg] * sAl[rr] + sBt[rr];
                short h = f2bf(v);
                size_t off = ((size_t)wi * 256 + vr) * L + (l0 + nl);
                v_hi[off] = h;
                v_lo[off] = f2bf(v - bf2f(h));
            }
        }
    }
}

// ---------------- Kernel 2: MFMA flash attention, wave-specialized ----------------
// 512 thr. waves 0-3: scores (16 keys each) + softmax; waves 4-7: K/V staging.
// PV: 32x32x16, all 8 waves, c-split (32 ch/wave). Terms: Ph*(Vh+Vl).
__global__ __launch_bounds__(512, 1) void attn_kernel(
    const short* __restrict__ qT_hi, const short* __restrict__ qT_lo,
    const short* __restrict__ kT_hi, const short* __restrict__ kT_lo,
    const short* __restrict__ v_hi,  const short* __restrict__ v_lo,
    short* __restrict__ ctx_hi, short* __restrict__ ctx_lo,
    int s, int si)
{
    const int L  = (64 / s) * (64 / s) * 2;
    const int nt = L >> 6;
    const int t  = threadIdx.x;
    const int w  = t >> 6;
    const int l  = t & 63;
    const int wi = blockIdx.y;
    const int q0 = blockIdx.x * 64;
    const int b  = wi & 1;

    __shared__ short sV[32768];               // [pl*16384 + swz(c, k*2, 128)/2] 256c x 64k
    __shared__ short sK2[2][2][2048];         // [buf][pl][swz(k, c*2, 64)/2]    64k x 32c
    __shared__ short sP[4096];                // [swz(q, k*2, 128)/2]            64q x 64k (hi)
    __shared__ float sPmax[4][64], sPsum[4][64];
    __shared__ float sRs[64];
    __shared__ int   sPmap[64];

    if (t < 64) {
        int lq = q0 + t;
        int hs = 64 / s, wsz = 64 / s;
        int i_blk = wi / (s * 2), j_blk = (wi / 2) % s;
        int hh = lq / (wsz * 2), rem = lq % (wsz * 2);
        sPmap[t] = (i_blk * hs + hh) * W2_ + (rem & 1) * 64 + j_blk * wsz + (rem >> 1);
    }

    // Q fragments in registers (waves 0-3)
    short8 qh[4], qlo[4];
    if (w < 4) {
        #pragma unroll
        for (int qt = 0; qt < 4; ++qt) {
            size_t off = (size_t)(wi * L + q0 + qt * 16 + (l & 15)) * 32 + (l >> 4) * 8;
            qh[qt]  = *(const short8*)&qT_hi[off];
            qlo[qt] = *(const short8*)&qT_lo[off];
        }
    }

    // staging decode (threads 256-511)
    const int ts = t & 255;
    const size_t vboff = (size_t)wi * 256 * L + (size_t)(ts >> 3) * L + (ts & 7) * 8;
    const int vlds0 = swz(ts >> 3, (ts & 7) * 16, 128) >> 1;
    const size_t kboff = (size_t)(wi * L + (ts >> 2)) * 32 + (ts & 3) * 8;
    const int klds0 = swz(ts >> 2, (ts & 3) * 16, 64) >> 1;   // FIXED: full-address swz (was chunk-only XOR -> desync with reader)

    short8 vreg[16], kregN[2];
    float mo = -1e30f, rl = 0.f;
    f32x16 acc0 = {}, acc1 = {};
    f32x4 sacc[4];

    if (w >= 4) {
        #pragma unroll
        for (int i = 0; i < 16; ++i) {
            const short* vp = (i < 8) ? v_hi : v_lo;
            vreg[i] = *(const short8*)&vp[vboff + (size_t)(i & 7) * 32 * L];
        }
        kregN[0] = *(const short8*)&kT_hi[kboff];
        kregN[1] = *(const short8*)&kT_lo[kboff];
        #pragma unroll
        for (int i = 0; i < 16; ++i)
            *(short8*)&sV[(i >> 3) * 16384 + vlds0 + (i & 7) * 2048] = vreg[i];
        *(short8*)&sK2[0][0][klds0] = kregN[0];
        *(short8*)&sK2[0][1][klds0] = kregN[1];
        if (nt > 1) {
            kregN[0] = *(const short8*)&kT_hi[kboff + 64 * 32];
            kregN[1] = *(const short8*)&kT_lo[kboff + 64 * 32];
        }
    }
    __syncthreads();

    int buf = 0;
    #pragma unroll 1
    for (int tt = 0; tt < nt; ++tt) {
        const bool more = (tt + 1 < nt);
        // -------- P1: scores (w<4) | stage K(t+1), issue V(t+1) loads (w>=4) --------
        if (w < 4) {
            const int krow = w * 16 + (l & 15);
            const int kidx = swz(krow, (l >> 4) * 16, 64) >> 1;
            short8 kbh = *(const short8*)&sK2[buf][0][kidx];
            short8 kbl = *(const short8*)&sK2[buf][1][kidx];
            #pragma unroll
            for (int qt = 0; qt < 4; ++qt) {
                f32x4 z = {0.f, 0.f, 0.f, 0.f};
                z = mfma16(qh[qt], kbh, z);
                z = mfma16(qlo[qt], kbh, z);
                z = mfma16(qh[qt], kbl, z);
                sacc[qt] = z;
            }
            #pragma unroll
            for (int qt = 0; qt < 4; ++qt) {
                float a0 = sacc[qt][0], a1 = sacc[qt][1], a2 = sacc[qt][2], a3 = sacc[qt][3];
                #pragma unroll
                for (int msk = 1; msk <= 8; msk <<= 1) {
                    a0 = fmaxf(a0, __shfl_xor(a0, msk));
                    a1 = fmaxf(a1, __shfl_xor(a1, msk));
                    a2 = fmaxf(a2, __shfl_xor(a2, msk));
                    a3 = fmaxf(a3, __shfl_xor(a3, msk));
                }
                if ((l & 15) == 0) {
                    int qb = qt * 16 + ((l >> 4) << 2);
                    sPmax[w][qb] = a0; sPmax[w][qb + 1] = a1;
                    sPmax[w][qb + 2] = a2; sPmax[w][qb + 3] = a3;
                }
            }
        } else if (more) {
            *(short8*)&sK2[buf ^ 1][0][klds0] = kregN[0];
            *(short8*)&sK2[buf ^ 1][1][klds0] = kregN[1];
            if (tt + 2 < nt) {
                kregN[0] = *(const short8*)&kT_hi[kboff + (size_t)(tt + 2) * 64 * 32];
                kregN[1] = *(const short8*)&kT_lo[kboff + (size_t)(tt + 2) * 64 * 32];
            }
            const size_t m1 = (size_t)(tt + 1) * 64;
            #pragma unroll
            for (int i = 0; i < 16; ++i) {
                const short* vp = (i < 8) ? v_hi : v_lo;
                vreg[i] = *(const short8*)&vp[vboff + (size_t)(i & 7) * 32 * L + m1];
            }
        }
        __syncthreads();                                   // B1
        // -------- P2: row stats (all, replicated) | exp + P write (w<4) --------
        float pm = fmaxf(fmaxf(sPmax[0][l], sPmax[1][l]),
                         fmaxf(sPmax[2][l], sPmax[3][l]));
        float mn = fmaxf(mo, pm);
        float scf = __expf(mo - mn);
        mo = mn;
        if (w == 7) sRs[l] = scf;
        if (w < 4) {
            #pragma unroll
            for (int qt = 0; qt < 4; ++qt) {
                float pr[4];
                #pragma unroll
                for (int r = 0; r < 4; ++r) {
                    int q = qt * 16 + ((l >> 4) << 2) + r;
                    float m = __shfl(mo, q);
                    float p = __expf(sacc[qt][r] - m);
                    pr[r] = p;
                    int so = swz(q, (w * 16 + (l & 15)) * 2, 128) >> 1;
                    sP[so] = f2bf(p);
                }
                float s0 = pr[0], s1 = pr[1], s2 = pr[2], s3 = pr[3];
                #pragma unroll
                for (int msk = 1; msk <= 8; msk <<= 1) {
                    s0 += __shfl_xor(s0, msk);
                    s1 += __shfl_xor(s1, msk);
                    s2 += __shfl_xor(s2, msk);
                    s3 += __shfl_xor(s3, msk);
                }
                if ((l & 15) == 0) {
                    int qb = qt * 16 + ((l >> 4) << 2);
                    sPsum[w][qb] = s0; sPsum[w][qb + 1] = s1;
                    sPsum[w][qb + 2] = s2; sPsum[w][qb + 3] = s3;
                }
            }
        }
        __syncthreads();                                   // B2
        // -------- P3: rescale + PV (all waves) --------
        rl = rl * scf + (sPsum[0][l] + sPsum[1][l] + sPsum[2][l] + sPsum[3][l]);
        #pragma unroll
        for (int reg = 0; reg < 16; ++reg) {
            int rowf = (reg & 3) + 8 * (reg >> 2) + 4 * (l >> 5);
            acc0[reg] *= sRs[rowf];
            acc1[reg] *= sRs[32 + rowf];
        }
        __builtin_amdgcn_s_setprio(1);
        #pragma unroll
        for (int kc = 0; kc < 4; ++kc) {
            const int ch = kc * 32 + (l >> 5) * 16;
            int r0 = l & 31;
            int pro0 = swz(r0, ch, 128) >> 1;
            int pro1 = swz(32 + r0, ch, 128) >> 1;
            int vrow = w * 32 + (l & 31);
            int vro = swz(vrow, ch, 128) >> 1;
            short8 pa0 = *(const short8*)&sP[pro0];
            short8 pa1 = *(const short8*)&sP[pro1];
            short8 vbh = *(const short8*)&sV[vro];
            short8 vbl = *(const short8*)&sV[16384 + vro];
            acc0 = mfma32(pa0, vbh, acc0);
            acc0 = mfma32(pa0, vbl, acc0);
            acc1 = mfma32(pa1, vbh, acc1);
            acc1 = mfma32(pa1, vbl, acc1);
        }
        __builtin_amdgcn_s_setprio(0);
        __syncthreads();                                   // B3
        // -------- P4: write V(t+1) (w>=4) --------
        if (w >= 4 && more) {
            #pragma unroll
            for (int i = 0; i < 16; ++i)
                *(short8*)&sV[(i >> 3) * 16384 + vlds0 + (i & 7) * 2048] = vreg[i];
        }
        buf ^= 1;
    }

    // -------- epilogue --------
    if (w == 7) sRs[l] = rl;
    __syncthreads();
    #pragma unroll
    for (int reg = 0; reg < 16; ++reg) {
        int rowf = (reg & 3) + 8 * (reg >> 2) + 4 * (l >> 5);
        int c = si * 256 + w * 32 + (l & 31);
        {
            float v = acc0[reg] / sRs[rowf];
            int p = sPmap[rowf];
            size_t off = ((size_t)(b * PP + p)) * 1024 + c;
            short h = f2bf(v);
            ctx_hi[off] = h;
            ctx_lo[off] = f2bf(v - bf2f(h));
        }
        {
            float v = acc1[reg] / sRs[32 + rowf];
            int p = sPmap[32 + rowf];
            size_t off = ((size_t)(b * PP + p)) * 1024 + c;
            short h = f2bf(v);
            ctx_hi[off] = h;
            ctx_lo[off] = f2bf(v - bf2f(h));
        }
    }
}

// ---------------- Kernel 3: 3x3 conv via MFMA (9 shifted GEMMs) + BN + ReLU ----------------
__global__ __launch_bounds__(512, 2) void conv_kernel(
    const short* __restrict__ ctx_hi, const short* __restrict__ ctx_lo,
    const short* __restrict__ wt_hi,  const short* __restrict__ wt_lo,
    const float* __restrict__ cb, const float* __restrict__ cg,
    const float* __restrict__ cbe, const float* __restrict__ cm,
    const float* __restrict__ cv, float* __restrict__ out)
{
    const int t = threadIdx.x, w = t >> 6, l = t & 63;
    const int bimg = blockIdx.x >> 6, y = blockIdx.x & 63;
    const int o0 = blockIdx.y * 128;
    const int mo = w >> 2, np = w & 3;

    __shared__ short sB[24960];
    __shared__ short sA[2][8192];
    __shared__ float sAl[128], sBt[128];

    if (t < 128) {
        int o = o0 + t;
        float sc = cg[o] / sqrtf(cv[o] + EPS_);
        sAl[t] = sc;
        sBt[t] = cb[o] * sc + cbe[o] - cm[o] * sc;
    }

    const short* gb[7]; int blds[7]; bool bok[7]; bool bval[7];
    #pragma unroll
    for (int i = 0; i < 7; ++i) {
        int cid = i * 512 + t;
        bval[i] = (cid < 3120);
        int cc = bval[i] ? cid : 0;
        int plane = cc / 1560, r2 = cc % 1560;
        int rr = r2 >> 2, cq = r2 & 3;
        int dyi = rr / 130, xx = rr % 130;
        int yy = y + dyi - 1, px = xx - 1;
        bool ok = (yy >= 0 && yy < HH_ && px >= 0 && px < W2_);
        bok[i] = ok;
        size_t p = ok ? ((size_t)bimg * PP + yy * W2_ + px) : 0;
        gb[i] = (plane ? ctx_lo : ctx_hi) + p * 1024 + cq * 8;
        blds[i] = plane * 12480 + (swz(rr, cq * 16, 64) >> 1);
    }
    const short* ga[2]; int alds[2];
    #pragma unroll
    for (int i = 0; i < 2; ++i) {
        int cid = i * 512 + t;
        int plane = cid >> 9, r2 = cid & 511;
        int o = r2 >> 2, cq = r2 & 3;
        ga[i] = (plane ? wt_lo : wt_hi) + (size_t)(o0 + o) * 1024 + cq * 8;
        alds[i] = plane * 4096 + (swz(o, cq * 16, 64) >> 1);
    }

    f32x4 acc[4][2] = {};
    const short8 z8 = {};

    #pragma unroll 1
    for (int c0 = 0; c0 < 1024; c0 += 32) {
        #pragma unroll
        for (int i = 0; i < 7; ++i) {
            if (bval[i]) {
                short8 v = bok[i] ? *(const short8*)(gb[i] + c0) : z8;
                *(short8*)&sB[blds[i]] = v;
            }
        }
        #pragma unroll
        for (int i = 0; i < 2; ++i) {
            short8 v = *(const short8*)(ga[i] + c0);
            *(short8*)&sA[0][alds[i]] = v;
        }
        __syncthreads();
        #pragma unroll
        for (int d = 0; d < 9; ++d) {
            if (d < 8) {
                #pragma unroll
                for (int i = 0; i < 2; ++i) {
                    short8 v = *(const short8*)(ga[i] + (size_t)(d + 1) * 262144 + c0);
                    *(short8*)&sA[(d + 1) & 1][alds[i]] = v;
                }
            }
            const int ky = d / 3, kx = d % 3;
            short8 ah[4], al[4];
            #pragma unroll
            for (int mf = 0; mf < 4; ++mf) {
                int ro = mo * 64 + mf * 16 + (l & 15);
                int so = swz(ro, (l >> 4) * 16, 64) >> 1;
                ah[mf] = *(const short8*)&sA[d & 1][so];
                al[mf] = *(const short8*)&sA[d & 1][4096 + so];
            }
            short8 bh[2], bl2[2];
            #pragma unroll
            for (int nf = 0; nf < 2; ++nf) {
                int rb = ky * 130 + np * 32 + nf * 16 + (l & 15) + kx;
                int so = swz(rb, (l >> 4) * 16, 64) >> 1;
                bh[nf]  = *(const short8*)&sB[so];
                bl2[nf] = *(const short8*)&sB[12480 + so];
            }
            #pragma unroll
            for (int mf = 0; mf < 4; ++mf)
                #pragma unroll
                for (int nf = 0; nf < 2; ++nf) {
                    acc[mf][nf] = mfma16(ah[mf], bh[nf],  acc[mf][nf]);
                    acc[mf][nf] = mfma16(ah[mf], bl2[nf], acc[mf][nf]);
                    acc[mf][nf] = mfma16(al[mf], bh[nf],  acc[mf][nf]);
                }
            __syncthreads();
        }
    }

    #pragma unroll
    for (int mf = 0; mf < 4; ++mf) {
        #pragma unroll
        for (int r = 0; r < 4; ++r) {
            int ol = mo * 64 + mf * 16 + ((l >> 4) << 2) + r;
            float a = sAl[ol], bt = sBt[ol];
            #pragma unroll
            for (int nf = 0; nf < 2; ++nf) {
                int x = np * 32 + nf * 16 + (l & 15);
                float v = fmaxf(fmaf(acc[mf][nf][r], a, bt), 0.f);
                out[((size_t)(bimg * 256 + o0 + ol)) * PP + y * W2_ + x] = v;
            }
        }
    }
}

// ---------------- host launch ----------------
extern "C" void kernel_launch(void* const* d_in, const int* in_sizes, int n_in,
                              void* d_out, int out_size, void* d_ws, size_t ws_size,
                              hipStream_t stream)
{
    const float* feats  = (const float*)d_in[0];
    const float* q_w    = (const float*)d_in[1];
    const float* q_b    = (const float*)d_in[2];
    const float* q_g    = (const float*)d_in[3];
    const float* q_be   = (const float*)d_in[4];
    const float* q_m    = (const float*)d_in[5];
    const float* q_v    = (const float*)d_in[6];
    const float* k_w    = (const float*)d_in[7];
    const float* k_b    = (const float*)d_in[8];
    const float* k_g    = (const float*)d_in[9];
    const float* k_be   = (const float*)d_in[10];
    const float* k_m    = (const float*)d_in[11];
    const float* k_v    = (const float*)d_in[12];
    const float* v_w    = (const float*)d_in[13];
    const float* v_b    = (const float*)d_in[14];
    const float* conv_w = (const float*)d_in[15];
    const float* conv_b = (const float*)d_in[16];
    const float* c_g    = (const float*)d_in[17];
    const float* c_be   = (const float*)d_in[18];
    const float* c_m    = (const float*)d_in[19];
    const float* c_v    = (const float*)d_in[20];

    short* ws     = (short*)d_ws;
    short* ctx_hi = ws;                   // 16,777,216
    short* ctx_lo = ws + 16777216;        // 16,777,216
    short* v_hi   = ws + 33554432;        //  4,194,304
    short* v_lo   = ws + 37748736;        //  4,194,304
    short* qT_hi  = ws + 41943040;        //    524,288
    short* qT_lo  = ws + 42467328;        //    524,288
    short* kT_hi  = ws + 42991616;        //    524,288
    short* kT_lo  = ws + 43515904;        //    524,288
    short* region = ws + 44040192;        //  4,718,592 (featsH first, wt after)
    short* featsH = region;
    short* wt_hi  = region;
    short* wt_lo  = region + 2359296;
    // total 48,758,784 shorts = 97,517,568 B (== round-2 footprint)

    fsplit_kernel<<<dim3(2048), dim3(256), 0, stream>>>(feats, featsH);

    const int sizes[4] = {1, 2, 4, 8};
    const int lgL[4] = {13, 11, 9, 7};
    for (int si = 0; si < 4; ++si) {
        int s = sizes[si];
        int L = (64 / s) * (64 / s) * 2;
        int NT = (L < 256) ? L : 256;
        int Nw = s * s * BN_;
        qkv_kernel<<<dim3(16384 / NT, 5), dim3(512), 0, stream>>>(
            featsH,
            q_w + si * 32 * 256, q_b + si * 32, q_g + si * 32, q_be + si * 32,
            q_m + si * 32, q_v + si * 32,
            k_w + si * 32 * 256, k_b + si * 32, k_g + si * 32, k_be + si * 32,
            k_m + si * 32, k_v + si * 32,
            v_w + si * 256 * 256, v_b + si * 256,
            qT_hi, qT_lo, kT_hi, kT_lo, v_hi, v_lo, s, lgL[si]);
        attn_kernel<<<dim3(L / 64, Nw), dim3(512), 0, stream>>>(
            qT_hi, qT_lo, kT_hi, kT_lo, v_hi, v_lo, ctx_hi, ctx_lo, s, si);
    }

    wsplit_kernel<<<dim3(256, 4), dim3(256), 0, stream>>>(conv_w, wt_hi, wt_lo);

    conv_kernel<<<dim3(128, 2), dim3(512), 0, stream>>>(
        ctx_hi, ctx_lo, wt_hi, wt_lo, conv_b, c_g, c_be, c_m, c_v, (float*)d_out);
}